// Round 1
// 168.457 us; speedup vs baseline: 1.0550x; 1.0550x over previous
//
#include <hip/hip_runtime.h>
#include <math.h>

#define NN 1024
#define FD 64
#define CH 32          // K*H
#define M1D 9
#define M2D 505
#define QH 253         // q in [0,252] stored
#define THALF 2273     // half-grid points
#define KPAD 4608
#define KSPLIT 16      // gemm K-split (512 blocks = 2/CU)
#define KCHUNK 288     // 4608/16 = 9*32
#define G1SZ 291456    // 9*253*64*2
#define G1KS 8         // K-split factor for g1

#define FSQRT(x) __builtin_amdgcn_sqrtf(x)
#define FRCP(x)  __builtin_amdgcn_rcpf(x)

typedef short short8 __attribute__((ext_vector_type(8)));
typedef float f32x4 __attribute__((ext_vector_type(4)));

__device__ __forceinline__ unsigned short f2bf(float x) {
    unsigned int u = __builtin_bit_cast(unsigned int, x);
    return (unsigned short)((u + 0x7FFFu + ((u >> 16) & 1u)) >> 16);
}

// ws layout (floats)
#define OFF_SUMXP 1024                    // 32*64 = 2048
#define OFF_GMT   4096                    // GmatT bf16 [64][4608] = 147456 floats
#define OFF_XL    151552                  // 65536
#define OFF_XR    217088                  // 65536
#define OFF_AGG   282624                  // 1048576
#define OFF_Y     1331200                 // Y bf16 [2048][4608] = 4718592 floats
#define OFF_G1P   6049792                 // 8*291456 = 2331648
// total = 8,381,440 floats = 33.5 MB

// ---------------------------------------------------------------------------
// K1: fused pre-pass.
//   blocks [0,576)     : g1 gemm (T twiddles computed inline)
//   blocks [576,1088)  : proj, 4 nodes per 256-thr block
//   blocks [1088,1096) : sumx partial column sums -> sumxp[32][64] (no atomics)
//   blocks [1096,1224) : out init = bm * mask (gemm atomics accumulate on top)
// ---------------------------------------------------------------------------
__global__ __launch_bounds__(256) void fused_pre_kernel(
    const float* __restrict__ x,
    const float* __restrict__ Wl, const float* __restrict__ bl,
    const float* __restrict__ Wr, const float* __restrict__ br,
    const float* __restrict__ Wm, const float* __restrict__ bm,
    const float* __restrict__ mask,
    float* __restrict__ xl, float* __restrict__ xr,
    float* __restrict__ sumxp, float* __restrict__ G1p,
    float* __restrict__ out)
{
    __shared__ float As[64][68];
    __shared__ float Bs[64][64];
    int bid = blockIdx.x, tid = threadIdx.x;

    if (bid < 576) {
        // ---- g1 gemm: G1 partials, grid (8 mt, 9 m1, 8 ks) flattened ----
        int mt = bid & 7, m1 = (bid >> 3) % 9, ks = bid / 72;
        int r0 = mt * 64, k0 = ks * 64;
        const float* Wmb = Wm + (size_t)m1 * M2D * FD;
        float ra[16], rb[16];
        #pragma unroll
        for (int i = 0; i < 16; i++) {
            int l = tid + i*256;
            int r = l >> 6, k = l & 63;
            int rr = r0 + r, m2 = k0 + k;
            float v = 0.f;
            if (rr < 506 && m2 < M2D) {
                int q = rr >> 1;
                int t = (q * m2) % M2D;
                float ang = (float)t * (-6.2831853f / 505.0f);
                float s, c; __sincosf(ang, &s, &c);
                v = (rr & 1) ? -s : c;
            }
            ra[i] = v;
        }
        #pragma unroll
        for (int i = 0; i < 16; i++) {
            int l = tid + i*256;
            int k = l >> 6, f = l & 63;
            int krow = k0 + k;
            rb[i] = (krow < M2D) ? Wmb[(size_t)krow*FD + f] : 0.f;
        }
        #pragma unroll
        for (int i = 0; i < 16; i++) {
            int l = tid + i*256;
            As[l & 63][l >> 6] = ra[i];
        }
        #pragma unroll
        for (int i = 0; i < 16; i++) {
            int l = tid + i*256;
            Bs[l >> 6][l & 63] = rb[i];
        }
        __syncthreads();
        float acc[4][4] = {{0.f}};
        int tm = (tid >> 4) * 4, tf = (tid & 15) * 4;
        #pragma unroll 8
        for (int k = 0; k < 64; k++) {
            float4 a = *(const float4*)&As[k][tm];
            float4 b = *(const float4*)&Bs[k][tf];
            acc[0][0] += a.x*b.x; acc[0][1] += a.x*b.y; acc[0][2] += a.x*b.z; acc[0][3] += a.x*b.w;
            acc[1][0] += a.y*b.x; acc[1][1] += a.y*b.y; acc[1][2] += a.y*b.z; acc[1][3] += a.y*b.w;
            acc[2][0] += a.z*b.x; acc[2][1] += a.z*b.y; acc[2][2] += a.z*b.z; acc[2][3] += a.z*b.w;
            acc[3][0] += a.w*b.x; acc[3][1] += a.w*b.y; acc[3][2] += a.w*b.z; acc[3][3] += a.w*b.w;
        }
        float* G1k = G1p + (size_t)ks * G1SZ;
        #pragma unroll
        for (int i = 0; i < 4; i++) {
            int r = r0 + tm + i;
            if (r >= 506) continue;
            int q = r >> 1, reim = r & 1;
            size_t base = (size_t)(m1*QH + q) * 128;
            #pragma unroll
            for (int j = 0; j < 4; j++)
                G1k[base + (tf + j)*2 + reim] = acc[i][j];
        }
    } else if (bid < 1088) {
        // ---- proj: 4 nodes per block ----
        int grp = tid >> 6, lt = tid & 63;
        int node = (bid - 576)*4 + grp;
        float* xrow = &As[0][0] + grp*FD;
        xrow[lt] = x[(size_t)node*FD + lt];
        __syncthreads();
        int c = lt & 31;
        const float* W = (lt < 32) ? Wl : Wr;
        float acc = (lt < 32) ? bl[c] : br[c];
        #pragma unroll
        for (int f = 0; f < FD; f++) acc += xrow[f] * W[f*CH + c];
        float* dst = (lt < 32) ? xl : xr;
        dst[(size_t)node*CH + c] = acc;
    } else if (bid < 1096) {
        // ---- sumx partials: 4 (b,chunk) pairs per block ----
        int bb = (bid - 1088)*4 + (tid >> 6);   // 0..31
        int f = tid & 63;
        int b = bb >> 4, chunk = bb & 15;
        const float* xb = x + (size_t)b * NN * FD;
        float acc = 0.f;
        int j0 = chunk * 64;
        #pragma unroll 4
        for (int j = j0; j < j0 + 64; j++) acc += xb[j*FD + f];
        sumxp[bb*64 + f] = acc;
    } else {
        // ---- out init: out = bm * mask ----
        int idx = (bid - 1096)*256 + tid;       // < 32768
        float4 bv = ((const float4*)bm)[idx & 15];
        float mk = mask[idx >> 4];
        bv.x *= mk; bv.y *= mk; bv.z *= mk; bv.w *= mk;
        ((float4*)out)[idx] = bv;
    }
}

// ---------------------------------------------------------------------------
// K2: fused mid-pass.
//   blocks [0,2048)    : attn_agg (per node; sumx folded from 16 partials)
//   blocks [2048,2624) : gmat (4 t per block; wp twiddles built in LDS)
// ---------------------------------------------------------------------------
__global__ __launch_bounds__(256) void fused_mid_kernel(
    const float* __restrict__ x, const float* __restrict__ adj,
    const float* __restrict__ xl, const float* __restrict__ xr,
    const float* __restrict__ sumxp, const float* __restrict__ G1p,
    float* __restrict__ agg, unsigned short* __restrict__ GmT)
{
    int bid = blockIdx.x, tid = threadIdx.x;

    if (bid >= 2048) {
        // ---- gmat: GmatT bf16 [f][k], folds 8 K-split partials + 9-pt DFT ----
        __shared__ float wps[18];
        if (tid < 9) {
            float s, c; __sincosf((float)tid * (-6.2831853f / 9.0f), &s, &c);
            wps[2*tid] = c; wps[2*tid+1] = s;
        }
        __syncthreads();
        int t = (bid - 2048)*4 + (tid >> 6);    // < 2304 = KPAD/2
        int f = tid & 63;
        if (t >= THALF) {
            *(unsigned int*)&GmT[(size_t)f*KPAD + 2*t] = 0u;
            return;
        }
        int p, q;
        if (t < QH) { p = 0; q = t; }
        else { int u = t - QH; p = 1 + u / M2D; q = u % M2D; }
        int qq = (q < QH) ? q : (M2D - q);
        float sgn = (q < QH) ? 1.f : -1.f;
        float gr = 0.f, gi = 0.f;
        #pragma unroll
        for (int m1 = 0; m1 < M1D; m1++) {
            size_t o = ((size_t)(m1*QH + qq)*FD + f)*2;
            float ar = 0.f, ai = 0.f;
            #pragma unroll
            for (int ks = 0; ks < G1KS; ks++) {
                ar += G1p[(size_t)ks*G1SZ + o];
                ai += G1p[(size_t)ks*G1SZ + o + 1];
            }
            ai *= sgn;
            int pm = (p * m1) % M1D;
            float cr = wps[2*pm], ci = -wps[2*pm+1];
            gr += ar*cr - ai*ci;
            gi += ar*ci + ai*cr;
        }
        float scale = (t == 0) ? (1.0f/4545.0f) : (2.0f/4545.0f);
        unsigned int pk = (unsigned int)f2bf(gr*scale) | ((unsigned int)f2bf(-gi*scale) << 16);
        *(unsigned int*)&GmT[(size_t)f*KPAD + 2*t] = pk;
        return;
    }

    // ---- attn_agg: one block per node ----
    int node = bid;
    int b = node >> 10;
    __shared__ float xr_s[CH], Zinv[CH], Sinv[CH];
    __shared__ float red16[16][CH];
    __shared__ int act_list[NN + 8];
    __shared__ int act_n;
    __shared__ float qv2[64][CH];

    if (tid < CH) xr_s[tid] = xr[(size_t)node*CH + tid];
    if (tid == 0) act_n = 0;
    __syncthreads();

    int c = tid & 31, jl = tid >> 5;
    const float* xlb = xl + ((size_t)b << 10) * CH;
    const float* adjrow = adj + (size_t)node * NN;

    int c2 = tid & 15, jl16 = tid >> 4;
    const float2* xlb2 = (const float2*)xlb;
    float xrcx = xr_s[2*c2], xrcy = xr_s[2*c2+1];
    float zx = 0.f, zy = 0.f;
    for (int j0 = jl16; j0 < NN; j0 += 128) {
        float2 sv[8];
        #pragma unroll
        for (int u = 0; u < 8; u++) sv[u] = xlb2[(size_t)(j0 + u*16)*16 + c2];
        #pragma unroll
        for (int u = 0; u < 8; u++) {
            float s0 = sv[u].x + xrcx; s0 = s0 > 0.f ? s0 : 0.01f * s0;
            float s1 = sv[u].y + xrcy; s1 = s1 > 0.f ? s1 : 0.01f * s1;
            zx += __expf(s0); zy += __expf(s1);
        }
    }
    red16[jl16][2*c2]   = zx;
    red16[jl16][2*c2+1] = zy;

    float av[4];
    #pragma unroll
    for (int u = 0; u < 4; u++) av[u] = adjrow[tid + u*256];
    __syncthreads();
    if (tid < CH) {
        float z = 0.f;
        #pragma unroll
        for (int r = 0; r < 16; r++) z += red16[r][tid];
        Zinv[tid] = FRCP(z);
    }
    #pragma unroll
    for (int u = 0; u < 4; u++)
        if (av[u] != 0.f) { int p = atomicAdd(&act_n, 1); act_list[p] = tid + u*256; }
    __syncthreads();
    int nact = act_n;

    int f = tid & 63, n0 = tid >> 6;
    int g = f >> 4;
    int c0 = n0*4 + g, c1 = (n0+4)*4 + g;
    const float* xb = x + ((size_t)b << 10) * FD;
    float acc0 = 0.f, acc1 = 0.f, sacc = 0.f;

    for (int base = 0; base < nact; base += 64) {
        int cnt = min(64, nact - base);
        int cntp = (cnt + 7) & ~7;
        for (int u = tid; u < (cnt << 5); u += 256) {
            int jj = u >> 5, cc = u & 31;
            int j = act_list[base + jj];
            float s = xlb[j*CH + cc] + xr_s[cc];
            s = s > 0.f ? s : 0.01f * s;
            float pv = __expf(s) * Zinv[cc];
            float qq = fmaxf(pv, 1e-6f) - 1e-6f;
            qv2[jj][cc] = qq;
            sacc += qq;
        }
        for (int u = tid + (cnt << 5); u < (cntp << 5); u += 256)
            qv2[u >> 5][u & 31] = 0.f;
        if (tid < cntp - cnt) act_list[base + cnt + tid] = act_list[base];
        __syncthreads();
        for (int jb = 0; jb < cntp; jb += 8) {
            float xv[8];
            #pragma unroll
            for (int u = 0; u < 8; u++) xv[u] = xb[act_list[base + jb + u]*FD + f];
            #pragma unroll
            for (int u = 0; u < 8; u++) {
                acc0 += qv2[jb+u][c0] * xv[u];
                acc1 += qv2[jb+u][c1] * xv[u];
            }
        }
        __syncthreads();
    }
    red16[jl][c] = sacc;
    __syncthreads();
    if (tid < CH) {
        float s = 0.f;
        #pragma unroll
        for (int r = 0; r < 8; r++) s += red16[r][tid];
        Sinv[tid] = FRCP(s + (float)NN * 1e-6f);
    }
    __syncthreads();
    float sx = 0.f;
    #pragma unroll
    for (int cchunk = 0; cchunk < 16; cchunk++) sx += sumxp[(b*16 + cchunk)*64 + f];
    sx *= 1e-6f;
    agg[(size_t)node*512 + n0*FD + f]       = (acc0 + sx) * Sinv[c0];
    agg[(size_t)node*512 + (n0+4)*FD + f]   = (acc1 + sx) * Sinv[c1];
}

// ---------------------------------------------------------------------------
// K3: fused A2-gemm + Y. Wt chunk twiddles computed inline (no table).
// ---------------------------------------------------------------------------
__global__ __launch_bounds__(256) void ay_kernel(const float* __restrict__ agg,
                                                 unsigned short* __restrict__ Yb) {
    int slab = blockIdx.x, nt = blockIdx.y;
    int tid = threadIdx.x;
    __shared__ float As2[64][68];   // phase 1: A-tile [k][row]; phase 2: A2 chunk [row][2q+reim]
    __shared__ float Bs[64][64];    // Wt chunk [k][col]
    int tm = (tid >> 4) * 4, tf = (tid & 15) * 4;
    float ra[16], rb[16];
    #pragma unroll
    for (int i = 0; i < 16; i++) {
        int l = tid + i*256;
        int r = l >> 6, k = l & 63;
        ra[i] = agg[(size_t)(slab*64 + r)*64 + k];
    }
    #pragma unroll
    for (int i = 0; i < 16; i++) {
        int l = tid + i*256;
        int k = l >> 6, cc = l & 63;
        int col = nt*64 + cc;
        float v = 0.f;
        if (col < 506) {
            int q = col >> 1;
            int tt = (q * k) % M2D;
            float ang = (float)tt * (-6.2831853f / 505.0f);
            float s, c; __sincosf(ang, &s, &c);
            v = (col & 1) ? s : c;
        }
        rb[i] = v;
    }
    #pragma unroll
    for (int i = 0; i < 16; i++) { int l = tid + i*256; As2[l & 63][l >> 6] = ra[i]; }
    #pragma unroll
    for (int i = 0; i < 16; i++) { int l = tid + i*256; Bs[l >> 6][l & 63] = rb[i]; }
    __syncthreads();
    float acc[4][4] = {{0.f}};
    #pragma unroll 8
    for (int k = 0; k < 64; k++) {
        float4 a = *(const float4*)&As2[k][tm];
        float4 b = *(const float4*)&Bs[k][tf];
        acc[0][0] += a.x*b.x; acc[0][1] += a.x*b.y; acc[0][2] += a.x*b.z; acc[0][3] += a.x*b.w;
        acc[1][0] += a.y*b.x; acc[1][1] += a.y*b.y; acc[1][2] += a.y*b.z; acc[1][3] += a.y*b.w;
        acc[2][0] += a.z*b.x; acc[2][1] += a.z*b.y; acc[2][2] += a.z*b.z; acc[2][3] += a.z*b.w;
        acc[3][0] += a.w*b.x; acc[3][1] += a.w*b.y; acc[3][2] += a.w*b.z; acc[3][3] += a.w*b.w;
    }
    __syncthreads();   // all As2 reads complete before overwrite
    #pragma unroll
    for (int i = 0; i < 4; i++)
        #pragma unroll
        for (int j = 0; j < 4; j++)
            As2[tm + i][tf + j] = acc[i][j];
    __syncthreads();

    // phase 2: Y for q = nt*32 + qloc, node = slab*8 + (tid>>5)
    int qloc = tid & 31, node = tid >> 5;
    unsigned short* Yrow = Yb + (size_t)(slab*8 + node)*KPAD;
    int q = nt*32 + qloc;

    if (q <= 252) {
        float2 Av[8];
        #pragma unroll
        for (int n = 0; n < 8; n++)
            Av[n] = make_float2(As2[node*8 + n][2*qloc], As2[node*8 + n][2*qloc + 1]);

        const float CPt[5] = {1.0f, 0.766044443119f, 0.173648177667f, -0.5f, -0.939692620786f};
        const float SPt[5] = {0.0f, -0.642787609687f, -0.984807753012f, -0.866025403784f, -0.342020143326f};

        #define Y_PROD(CSIGN, TIDX)                                            \
        {                                                                      \
            float Pr = 1.f, Pi = 0.f, rp2 = 1.f;                               \
            _Pragma("unroll")                                                  \
            for (int n = 0; n < 8; n++) {                                      \
                float Xr = cp - Av[n].x, Xi = sp - (CSIGN) * Av[n].y;          \
                rp2 *= (Xr*Xr + Xi*Xi);                                        \
                float nPr = Pr*Xr - Pi*Xi;                                     \
                Pi = Pr*Xi + Pi*Xr; Pr = nPr;                                  \
            }                                                                  \
            float pAbs = FSQRT(Pr*Pr + Pi*Pi);                                 \
            float rp8 = FSQRT(FSQRT(FSQRT(FSQRT(rp2))));                       \
            float s = rp8 * FRCP(fmaxf(pAbs, 1e-20f));                         \
            unsigned int pk = (unsigned int)f2bf(s*Pr) | ((unsigned int)f2bf(s*Pi) << 16); \
            *(unsigned int*)&Yrow[2*(TIDX)] = pk;                              \
        }

        #pragma unroll
        for (int p = 0; p < 5; p++) {
            float cp = CPt[p], sp = SPt[p];
            int tfwd = (p == 0) ? q : (QH + (p-1)*M2D + q);
            Y_PROD(1.f, tfwd);
            if (p >= 1 && q >= 1) {
                int tmir = QH + (p-1)*M2D + (M2D - q);
                Y_PROD(-1.f, tmir);
            }
        }
        #undef Y_PROD
    }
    // zero the pad region [2*THALF, KPAD) for the slab's 8 rows (nt==7 blocks)
    if (nt == 7 && tid < 248) {
        int rr = tid / 31, cc2 = tid % 31;
        unsigned short* Yr2 = Yb + (size_t)(slab*8 + rr)*KPAD;
        *(unsigned int*)&Yr2[2*THALF + 2*cc2] = 0u;
    }
}

// ---------------------------------------------------------------------------
// K4: MFMA bf16 gemm, atomic epilogue straight into out (pre-init'd bm*mask).
// ---------------------------------------------------------------------------
__global__ __launch_bounds__(256) void gemm_kernel(const unsigned short* __restrict__ Yb,
                                                   const unsigned short* __restrict__ GmT,
                                                   const float* __restrict__ mask,
                                                   float* __restrict__ out) {
    int mtile = blockIdx.x, kc = blockIdx.y;
    int tid = threadIdx.x;
    __shared__ unsigned short Ys[64*40];   // [m][k], stride 40 bf16
    __shared__ unsigned short Gs[64*40];   // [n][k], stride 40
    int m0 = mtile * 64;
    int k0 = kc * KCHUNK;
    int r = tid >> 2, kg = (tid & 3) * 8;
    const unsigned short* Ysrc = Yb + (size_t)(m0 + r)*KPAD + k0 + kg;
    const unsigned short* Gsrc = GmT + (size_t)r*KPAD + k0 + kg;
    uint4 ya = *(const uint4*)Ysrc;
    uint4 ga = *(const uint4*)Gsrc;
    int w = tid >> 6, lane = tid & 63;
    int lm = lane & 15, quad = lane >> 4;
    f32x4 acc0 = {0.f,0.f,0.f,0.f}, acc1 = acc0, acc2 = acc0, acc3 = acc0;
    for (int ks = 0; ks < KCHUNK; ks += 32) {
        *(uint4*)&Ys[r*40 + kg] = ya;
        *(uint4*)&Gs[r*40 + kg] = ga;
        __syncthreads();
        if (ks + 32 < KCHUNK) {
            ya = *(const uint4*)(Ysrc + ks + 32);
            ga = *(const uint4*)(Gsrc + ks + 32);
        }
        short8 b  = *(const short8*)&Gs[(w*16 + lm)*40 + quad*8];
        short8 a0 = *(const short8*)&Ys[(lm)*40      + quad*8];
        short8 a1 = *(const short8*)&Ys[(16 + lm)*40 + quad*8];
        short8 a2 = *(const short8*)&Ys[(32 + lm)*40 + quad*8];
        short8 a3 = *(const short8*)&Ys[(48 + lm)*40 + quad*8];
        acc0 = __builtin_amdgcn_mfma_f32_16x16x32_bf16(a0, b, acc0, 0, 0, 0);
        acc1 = __builtin_amdgcn_mfma_f32_16x16x32_bf16(a1, b, acc1, 0, 0, 0);
        acc2 = __builtin_amdgcn_mfma_f32_16x16x32_bf16(a2, b, acc2, 0, 0, 0);
        acc3 = __builtin_amdgcn_mfma_f32_16x16x32_bf16(a3, b, acc3, 0, 0, 0);
        __syncthreads();
    }
    int col = w*16 + lm;
    #pragma unroll
    for (int rr = 0; rr < 4; rr++) {
        int row = m0 + quad*4 + rr;
        atomicAdd(&out[(size_t)row*FD + col],        acc0[rr] * mask[row]);
        atomicAdd(&out[(size_t)(row+16)*FD + col],   acc1[rr] * mask[row+16]);
        atomicAdd(&out[(size_t)(row+32)*FD + col],   acc2[rr] * mask[row+32]);
        atomicAdd(&out[(size_t)(row+48)*FD + col],   acc3[rr] * mask[row+48]);
    }
}

extern "C" void kernel_launch(void* const* d_in, const int* in_sizes, int n_in,
                              void* d_out, int out_size, void* d_ws, size_t ws_size,
                              hipStream_t stream) {
    const float* x    = (const float*)d_in[0];
    const float* adj  = (const float*)d_in[1];
    const float* mask = (const float*)d_in[2];
    const float* Wl   = (const float*)d_in[3];
    const float* bl   = (const float*)d_in[4];
    const float* Wr   = (const float*)d_in[5];
    const float* br   = (const float*)d_in[6];
    const float* Wm   = (const float*)d_in[9];
    const float* bm   = (const float*)d_in[10];
    float* out = (float*)d_out;
    float* ws  = (float*)d_ws;

    float* sumxp = ws + OFF_SUMXP;
    unsigned short* GmT = (unsigned short*)(ws + OFF_GMT);
    float* xl   = ws + OFF_XL;
    float* xr   = ws + OFF_XR;
    float* agg  = ws + OFF_AGG;
    unsigned short* Yb = (unsigned short*)(ws + OFF_Y);
    float* G1p  = ws + OFF_G1P;

    hipLaunchKernelGGL(fused_pre_kernel, dim3(1224), dim3(256), 0, stream,
                       x, Wl, bl, Wr, br, Wm, bm, mask, xl, xr, sumxp, G1p, out);
    hipLaunchKernelGGL(fused_mid_kernel, dim3(2624), dim3(256), 0, stream,
                       x, adj, xl, xr, sumxp, G1p, agg, GmT);
    hipLaunchKernelGGL(ay_kernel, dim3(256, 8), dim3(256), 0, stream, agg, Yb);
    hipLaunchKernelGGL(gemm_kernel, dim3(32, KSPLIT), dim3(256), 0, stream, Yb, GmT, mask, out);
}

// Round 2
// 159.583 us; speedup vs baseline: 1.1136x; 1.0556x over previous
//
#include <hip/hip_runtime.h>
#include <math.h>

#define NN 1024
#define FD 64
#define CH 32          // K*H
#define M1D 9
#define M2D 505
#define QH 253         // q in [0,252] stored
#define THALF 2273     // half-grid points
#define KPAD 4608
#define KSPLIT 16      // gemm K-split (512 blocks = 2/CU)
#define KCHUNK 288     // 4608/16 = 9*32
#define G1SZ 291456    // 9*253*128 (planar: [m1*253+q][reim][64])
#define G1KS 8         // K-split factor for g1

#define FSQRT(x) __builtin_amdgcn_sqrtf(x)
#define FRCP(x)  __builtin_amdgcn_rcpf(x)

typedef short short8 __attribute__((ext_vector_type(8)));
typedef float f32x4 __attribute__((ext_vector_type(4)));

__device__ __forceinline__ unsigned short f2bf(float x) {
    unsigned int u = __builtin_bit_cast(unsigned int, x);
    return (unsigned short)((u + 0x7FFFu + ((u >> 16) & 1u)) >> 16);
}

// ws layout (floats)
#define OFF_SUMXP 1024                    // 32*64 = 2048
#define OFF_GMT   4096                    // GmatT bf16 [64][4608] = 147456 floats
#define OFF_XL    151552                  // 65536
#define OFF_XR    217088                  // 65536
#define OFF_AGG   282624                  // 1048576
#define OFF_Y     1331200                 // Y bf16 [2048][4608] = 4718592 floats
#define OFF_G1P   6049792                 // 8*291456 = 2331648
#define OFF_WT    8381440                 // 64*512 = 32768
// total = 8,414,208 floats = 33.7 MB

// ---------------------------------------------------------------------------
// K1: fused pre-pass.
//   blocks [0,576)     : g1 gemm (T twiddles inline; planar G1p write)
//   blocks [576,1088)  : proj, 4 nodes per 256-thr block
//   blocks [1088,1096) : sumx partial column sums -> sumxp[32][64]
//   blocks [1096,1224) : out init = bm * mask
//   blocks [1224,1352) : Wt table build [64][512] (bit-identical sincos)
// ---------------------------------------------------------------------------
__global__ __launch_bounds__(256) void fused_pre_kernel(
    const float* __restrict__ x,
    const float* __restrict__ Wl, const float* __restrict__ bl,
    const float* __restrict__ Wr, const float* __restrict__ br,
    const float* __restrict__ Wm, const float* __restrict__ bm,
    const float* __restrict__ mask,
    float* __restrict__ xl, float* __restrict__ xr,
    float* __restrict__ sumxp, float* __restrict__ G1p,
    float* __restrict__ Wt, float* __restrict__ out)
{
    __shared__ float As[64][68];
    __shared__ float Bs[64][64];
    int bid = blockIdx.x, tid = threadIdx.x;

    if (bid < 576) {
        // ---- g1 gemm: G1 partials, grid (8 mt, 9 m1, 8 ks) flattened ----
        int mt = bid & 7, m1 = (bid >> 3) % 9, ks = bid / 72;
        int r0 = mt * 64, k0 = ks * 64;
        const float* Wmb = Wm + (size_t)m1 * M2D * FD;
        float ra[16], rb[16];
        #pragma unroll
        for (int i = 0; i < 16; i++) {
            int l = tid + i*256;
            int r = l >> 6, k = l & 63;
            int rr = r0 + r, m2 = k0 + k;
            float v = 0.f;
            if (rr < 506 && m2 < M2D) {
                int q = rr >> 1;
                int t = (q * m2) % M2D;
                float ang = (float)t * (-6.2831853f / 505.0f);
                float s, c; __sincosf(ang, &s, &c);
                v = (rr & 1) ? -s : c;
            }
            ra[i] = v;
        }
        #pragma unroll
        for (int i = 0; i < 16; i++) {
            int l = tid + i*256;
            int k = l >> 6, f = l & 63;
            int krow = k0 + k;
            rb[i] = (krow < M2D) ? Wmb[(size_t)krow*FD + f] : 0.f;
        }
        #pragma unroll
        for (int i = 0; i < 16; i++) {
            int l = tid + i*256;
            As[l & 63][l >> 6] = ra[i];
        }
        #pragma unroll
        for (int i = 0; i < 16; i++) {
            int l = tid + i*256;
            Bs[l >> 6][l & 63] = rb[i];
        }
        __syncthreads();
        float acc[4][4] = {{0.f}};
        int tm = (tid >> 4) * 4, tf = (tid & 15) * 4;
        #pragma unroll 8
        for (int k = 0; k < 64; k++) {
            float4 a = *(const float4*)&As[k][tm];
            float4 b = *(const float4*)&Bs[k][tf];
            acc[0][0] += a.x*b.x; acc[0][1] += a.x*b.y; acc[0][2] += a.x*b.z; acc[0][3] += a.x*b.w;
            acc[1][0] += a.y*b.x; acc[1][1] += a.y*b.y; acc[1][2] += a.y*b.z; acc[1][3] += a.y*b.w;
            acc[2][0] += a.z*b.x; acc[2][1] += a.z*b.y; acc[2][2] += a.z*b.z; acc[2][3] += a.z*b.w;
            acc[3][0] += a.w*b.x; acc[3][1] += a.w*b.y; acc[3][2] += a.w*b.z; acc[3][3] += a.w*b.w;
        }
        float* G1k = G1p + (size_t)ks * G1SZ;
        #pragma unroll
        for (int i = 0; i < 4; i++) {
            int r = r0 + tm + i;
            if (r >= 506) continue;
            int q = r >> 1, reim = r & 1;
            size_t base = (size_t)(m1*QH + q) * 128 + reim*64;
            #pragma unroll
            for (int j = 0; j < 4; j++)
                G1k[base + tf + j] = acc[i][j];
        }
    } else if (bid < 1088) {
        // ---- proj: 4 nodes per block ----
        int grp = tid >> 6, lt = tid & 63;
        int node = (bid - 576)*4 + grp;
        float* xrow = &As[0][0] + grp*FD;
        xrow[lt] = x[(size_t)node*FD + lt];
        __syncthreads();
        int c = lt & 31;
        const float* W = (lt < 32) ? Wl : Wr;
        float acc = (lt < 32) ? bl[c] : br[c];
        #pragma unroll
        for (int f = 0; f < FD; f++) acc += xrow[f] * W[f*CH + c];
        float* dst = (lt < 32) ? xl : xr;
        dst[(size_t)node*CH + c] = acc;
    } else if (bid < 1096) {
        // ---- sumx partials: 4 (b,chunk) pairs per block ----
        int bb = (bid - 1088)*4 + (tid >> 6);   // 0..31
        int f = tid & 63;
        int b = bb >> 4, chunk = bb & 15;
        const float* xb = x + (size_t)b * NN * FD;
        float acc = 0.f;
        int j0 = chunk * 64;
        #pragma unroll 4
        for (int j = j0; j < j0 + 64; j++) acc += xb[j*FD + f];
        sumxp[bb*64 + f] = acc;
    } else if (bid < 1224) {
        // ---- out init: out = bm * mask ----
        int idx = (bid - 1096)*256 + tid;       // < 32768
        float4 bv = ((const float4*)bm)[idx & 15];
        float mk = mask[idx >> 4];
        bv.x *= mk; bv.y *= mk; bv.z *= mk; bv.w *= mk;
        ((float4*)out)[idx] = bv;
    } else {
        // ---- Wt table: [m=64][col=512], same expressions as before ----
        int idx = (bid - 1224)*256 + tid;       // < 32768
        int m = idx >> 9, col = idx & 511;
        float v = 0.f;
        if (col < 506) {
            int q = col >> 1;
            int t = (q * m) % M2D;
            float ang = (float)t * (-6.2831853f / 505.0f);
            float s, c; __sincosf(ang, &s, &c);
            v = (col & 1) ? s : c;
        }
        Wt[idx] = v;
    }
}

// ---------------------------------------------------------------------------
// K2: fused mid-pass.
//   blocks [0,2048)     : attn_agg (per node)
//   blocks [2048,2112)  : gmat v2 — per-qq: fold 8 partials ONCE (coalesced
//                         planar reads), emit all 9 half-grid outputs
//   block  2112         : GmT pad-zero t in [THALF, 2304)
// ---------------------------------------------------------------------------
__global__ __launch_bounds__(256) void fused_mid_kernel(
    const float* __restrict__ x, const float* __restrict__ adj,
    const float* __restrict__ xl, const float* __restrict__ xr,
    const float* __restrict__ sumxp, const float* __restrict__ G1p,
    float* __restrict__ agg, unsigned short* __restrict__ GmT)
{
    int bid = blockIdx.x, tid = threadIdx.x;

    if (bid >= 2048) {
        int bid2 = bid - 2048;
        if (bid2 == 64) {
            // pad region: t in [THALF, KPAD/2), all f
            for (int i = tid; i < 31*64; i += 256) {
                int t = THALF + (i >> 6), f = i & 63;
                *(unsigned int*)&GmT[(size_t)f*KPAD + 2*t] = 0u;
            }
            return;
        }
        __shared__ float wps[18];
        if (tid < 9) {
            float s, c; __sincosf((float)tid * (-6.2831853f / 9.0f), &s, &c);
            wps[2*tid] = c; wps[2*tid+1] = s;
        }
        __syncthreads();
        int qq = bid2*4 + (tid >> 6);
        int f = tid & 63;
        if (qq >= QH) return;
        // fold the 8 K-split partials once, coalesced (planar layout)
        float ar[M1D], ai[M1D];
        #pragma unroll
        for (int m1 = 0; m1 < M1D; m1++) {
            size_t o = (size_t)(m1*QH + qq) * 128 + f;
            float sr = 0.f, si = 0.f;
            #pragma unroll
            for (int ks = 0; ks < G1KS; ks++) {
                sr += G1p[(size_t)ks*G1SZ + o];
                si += G1p[(size_t)ks*G1SZ + o + 64];
            }
            ar[m1] = sr; ai[m1] = si;
        }
        // emit: p=0 (q=qq) and p=1..4 (q=qq, q=M2D-qq)
        #pragma unroll
        for (int p = 0; p < 5; p++) {
            {
                int t = (p == 0) ? qq : (QH + (p-1)*M2D + qq);
                float gr = 0.f, gi = 0.f;
                #pragma unroll
                for (int m1 = 0; m1 < M1D; m1++) {
                    int pm = (p * m1) % M1D;
                    float cr = wps[2*pm], ci = -wps[2*pm+1];
                    gr += ar[m1]*cr - ai[m1]*ci;
                    gi += ar[m1]*ci + ai[m1]*cr;
                }
                float scale = (t == 0) ? (1.0f/4545.0f) : (2.0f/4545.0f);
                unsigned int pk = (unsigned int)f2bf(gr*scale) | ((unsigned int)f2bf(-gi*scale) << 16);
                *(unsigned int*)&GmT[(size_t)f*KPAD + 2*t] = pk;
            }
            if (p >= 1 && qq >= 1) {
                int t = QH + (p-1)*M2D + (M2D - qq);
                float gr = 0.f, gi = 0.f;
                #pragma unroll
                for (int m1 = 0; m1 < M1D; m1++) {
                    int pm = (p * m1) % M1D;
                    float cr = wps[2*pm], ci = -wps[2*pm+1];
                    float aim = -ai[m1];            // sgn = -1 (Hermitian mirror)
                    gr += ar[m1]*cr - aim*ci;
                    gi += ar[m1]*ci + aim*cr;
                }
                float scale = 2.0f/4545.0f;         // t>0 always here
                unsigned int pk = (unsigned int)f2bf(gr*scale) | ((unsigned int)f2bf(-gi*scale) << 16);
                *(unsigned int*)&GmT[(size_t)f*KPAD + 2*t] = pk;
            }
        }
        return;
    }

    // ---- attn_agg: one block per node ----
    int node = bid;
    int b = node >> 10;
    __shared__ float xr_s[CH], Zinv[CH], Sinv[CH];
    __shared__ float red16[16][CH];
    __shared__ int act_list[NN + 8];
    __shared__ int act_n;
    __shared__ float qv2[64][CH];

    if (tid < CH) xr_s[tid] = xr[(size_t)node*CH + tid];
    if (tid == 0) act_n = 0;
    __syncthreads();

    int c = tid & 31, jl = tid >> 5;
    const float* xlb = xl + ((size_t)b << 10) * CH;
    const float* adjrow = adj + (size_t)node * NN;

    int c2 = tid & 15, jl16 = tid >> 4;
    const float2* xlb2 = (const float2*)xlb;
    float xrcx = xr_s[2*c2], xrcy = xr_s[2*c2+1];
    float zx = 0.f, zy = 0.f;
    for (int j0 = jl16; j0 < NN; j0 += 128) {
        float2 sv[8];
        #pragma unroll
        for (int u = 0; u < 8; u++) sv[u] = xlb2[(size_t)(j0 + u*16)*16 + c2];
        #pragma unroll
        for (int u = 0; u < 8; u++) {
            float s0 = sv[u].x + xrcx; s0 = s0 > 0.f ? s0 : 0.01f * s0;
            float s1 = sv[u].y + xrcy; s1 = s1 > 0.f ? s1 : 0.01f * s1;
            zx += __expf(s0); zy += __expf(s1);
        }
    }
    red16[jl16][2*c2]   = zx;
    red16[jl16][2*c2+1] = zy;

    float av[4];
    #pragma unroll
    for (int u = 0; u < 4; u++) av[u] = adjrow[tid + u*256];
    __syncthreads();
    if (tid < CH) {
        float z = 0.f;
        #pragma unroll
        for (int r = 0; r < 16; r++) z += red16[r][tid];
        Zinv[tid] = FRCP(z);
    }
    #pragma unroll
    for (int u = 0; u < 4; u++)
        if (av[u] != 0.f) { int p = atomicAdd(&act_n, 1); act_list[p] = tid + u*256; }
    __syncthreads();
    int nact = act_n;

    int f = tid & 63, n0 = tid >> 6;
    int g = f >> 4;
    int c0 = n0*4 + g, c1 = (n0+4)*4 + g;
    const float* xb = x + ((size_t)b << 10) * FD;
    float acc0 = 0.f, acc1 = 0.f, sacc = 0.f;

    for (int base = 0; base < nact; base += 64) {
        int cnt = min(64, nact - base);
        int cntp = (cnt + 7) & ~7;
        for (int u = tid; u < (cnt << 5); u += 256) {
            int jj = u >> 5, cc = u & 31;
            int j = act_list[base + jj];
            float s = xlb[j*CH + cc] + xr_s[cc];
            s = s > 0.f ? s : 0.01f * s;
            float pv = __expf(s) * Zinv[cc];
            float qq = fmaxf(pv, 1e-6f) - 1e-6f;
            qv2[jj][cc] = qq;
            sacc += qq;
        }
        for (int u = tid + (cnt << 5); u < (cntp << 5); u += 256)
            qv2[u >> 5][u & 31] = 0.f;
        if (tid < cntp - cnt) act_list[base + cnt + tid] = act_list[base];
        __syncthreads();
        for (int jb = 0; jb < cntp; jb += 8) {
            float xv[8];
            #pragma unroll
            for (int u = 0; u < 8; u++) xv[u] = xb[act_list[base + jb + u]*FD + f];
            #pragma unroll
            for (int u = 0; u < 8; u++) {
                acc0 += qv2[jb+u][c0] * xv[u];
                acc1 += qv2[jb+u][c1] * xv[u];
            }
        }
        __syncthreads();
    }
    red16[jl][c] = sacc;
    __syncthreads();
    if (tid < CH) {
        float s = 0.f;
        #pragma unroll
        for (int r = 0; r < 8; r++) s += red16[r][tid];
        Sinv[tid] = FRCP(s + (float)NN * 1e-6f);
    }
    __syncthreads();
    float sx = 0.f;
    #pragma unroll
    for (int cchunk = 0; cchunk < 16; cchunk++) sx += sumxp[(b*16 + cchunk)*64 + f];
    sx *= 1e-6f;
    agg[(size_t)node*512 + n0*FD + f]       = (acc0 + sx) * Sinv[c0];
    agg[(size_t)node*512 + (n0+4)*FD + f]   = (acc1 + sx) * Sinv[c1];
}

// ---------------------------------------------------------------------------
// K3: fused A2-gemm + Y. Wt chunk loaded from table (built in K1).
// ---------------------------------------------------------------------------
__global__ __launch_bounds__(256) void ay_kernel(const float* __restrict__ agg,
                                                 const float* __restrict__ Wt,
                                                 unsigned short* __restrict__ Yb) {
    int slab = blockIdx.x, nt = blockIdx.y;
    int tid = threadIdx.x;
    __shared__ float As2[64][68];   // phase 1: A-tile [k][row]; phase 2: A2 chunk [row][2q+reim]
    __shared__ float Bs[64][64];    // Wt chunk [k][col]
    int tm = (tid >> 4) * 4, tf = (tid & 15) * 4;
    float ra[16], rb[16];
    #pragma unroll
    for (int i = 0; i < 16; i++) {
        int l = tid + i*256;
        int r = l >> 6, k = l & 63;
        ra[i] = agg[(size_t)(slab*64 + r)*64 + k];
    }
    #pragma unroll
    for (int i = 0; i < 16; i++) {
        int l = tid + i*256;
        rb[i] = Wt[(size_t)(l >> 6)*512 + nt*64 + (l & 63)];
    }
    #pragma unroll
    for (int i = 0; i < 16; i++) { int l = tid + i*256; As2[l & 63][l >> 6] = ra[i]; }
    #pragma unroll
    for (int i = 0; i < 16; i++) { int l = tid + i*256; Bs[l >> 6][l & 63] = rb[i]; }
    __syncthreads();
    float acc[4][4] = {{0.f}};
    #pragma unroll 8
    for (int k = 0; k < 64; k++) {
        float4 a = *(const float4*)&As2[k][tm];
        float4 b = *(const float4*)&Bs[k][tf];
        acc[0][0] += a.x*b.x; acc[0][1] += a.x*b.y; acc[0][2] += a.x*b.z; acc[0][3] += a.x*b.w;
        acc[1][0] += a.y*b.x; acc[1][1] += a.y*b.y; acc[1][2] += a.y*b.z; acc[1][3] += a.y*b.w;
        acc[2][0] += a.z*b.x; acc[2][1] += a.z*b.y; acc[2][2] += a.z*b.z; acc[2][3] += a.z*b.w;
        acc[3][0] += a.w*b.x; acc[3][1] += a.w*b.y; acc[3][2] += a.w*b.z; acc[3][3] += a.w*b.w;
    }
    __syncthreads();   // all As2 reads complete before overwrite
    #pragma unroll
    for (int i = 0; i < 4; i++)
        #pragma unroll
        for (int j = 0; j < 4; j++)
            As2[tm + i][tf + j] = acc[i][j];
    __syncthreads();

    // phase 2: Y for q = nt*32 + qloc, node = slab*8 + (tid>>5)
    int qloc = tid & 31, node = tid >> 5;
    unsigned short* Yrow = Yb + (size_t)(slab*8 + node)*KPAD;
    int q = nt*32 + qloc;

    if (q <= 252) {
        float2 Av[8];
        #pragma unroll
        for (int n = 0; n < 8; n++)
            Av[n] = make_float2(As2[node*8 + n][2*qloc], As2[node*8 + n][2*qloc + 1]);

        const float CPt[5] = {1.0f, 0.766044443119f, 0.173648177667f, -0.5f, -0.939692620786f};
        const float SPt[5] = {0.0f, -0.642787609687f, -0.984807753012f, -0.866025403784f, -0.342020143326f};

        #define Y_PROD(CSIGN, TIDX)                                            \
        {                                                                      \
            float Pr = 1.f, Pi = 0.f, rp2 = 1.f;                               \
            _Pragma("unroll")                                                  \
            for (int n = 0; n < 8; n++) {                                      \
                float Xr = cp - Av[n].x, Xi = sp - (CSIGN) * Av[n].y;          \
                rp2 *= (Xr*Xr + Xi*Xi);                                        \
                float nPr = Pr*Xr - Pi*Xi;                                     \
                Pi = Pr*Xi + Pi*Xr; Pr = nPr;                                  \
            }                                                                  \
            float pAbs = FSQRT(Pr*Pr + Pi*Pi);                                 \
            float rp8 = FSQRT(FSQRT(FSQRT(FSQRT(rp2))));                       \
            float s = rp8 * FRCP(fmaxf(pAbs, 1e-20f));                         \
            unsigned int pk = (unsigned int)f2bf(s*Pr) | ((unsigned int)f2bf(s*Pi) << 16); \
            *(unsigned int*)&Yrow[2*(TIDX)] = pk;                              \
        }

        #pragma unroll
        for (int p = 0; p < 5; p++) {
            float cp = CPt[p], sp = SPt[p];
            int tfwd = (p == 0) ? q : (QH + (p-1)*M2D + q);
            Y_PROD(1.f, tfwd);
            if (p >= 1 && q >= 1) {
                int tmir = QH + (p-1)*M2D + (M2D - q);
                Y_PROD(-1.f, tmir);
            }
        }
        #undef Y_PROD
    }
    // zero the pad region [2*THALF, KPAD) for the slab's 8 rows (nt==7 blocks)
    if (nt == 7 && tid < 248) {
        int rr = tid / 31, cc2 = tid % 31;
        unsigned short* Yr2 = Yb + (size_t)(slab*8 + rr)*KPAD;
        *(unsigned int*)&Yr2[2*THALF + 2*cc2] = 0u;
    }
}

// ---------------------------------------------------------------------------
// K4: MFMA bf16 gemm, atomic epilogue straight into out (pre-init'd bm*mask).
// ---------------------------------------------------------------------------
__global__ __launch_bounds__(256) void gemm_kernel(const unsigned short* __restrict__ Yb,
                                                   const unsigned short* __restrict__ GmT,
                                                   const float* __restrict__ mask,
                                                   float* __restrict__ out) {
    int mtile = blockIdx.x, kc = blockIdx.y;
    int tid = threadIdx.x;
    __shared__ unsigned short Ys[64*40];   // [m][k], stride 40 bf16
    __shared__ unsigned short Gs[64*40];   // [n][k], stride 40
    int m0 = mtile * 64;
    int k0 = kc * KCHUNK;
    int r = tid >> 2, kg = (tid & 3) * 8;
    const unsigned short* Ysrc = Yb + (size_t)(m0 + r)*KPAD + k0 + kg;
    const unsigned short* Gsrc = GmT + (size_t)r*KPAD + k0 + kg;
    uint4 ya = *(const uint4*)Ysrc;
    uint4 ga = *(const uint4*)Gsrc;
    int w = tid >> 6, lane = tid & 63;
    int lm = lane & 15, quad = lane >> 4;
    f32x4 acc0 = {0.f,0.f,0.f,0.f}, acc1 = acc0, acc2 = acc0, acc3 = acc0;
    for (int ks = 0; ks < KCHUNK; ks += 32) {
        *(uint4*)&Ys[r*40 + kg] = ya;
        *(uint4*)&Gs[r*40 + kg] = ga;
        __syncthreads();
        if (ks + 32 < KCHUNK) {
            ya = *(const uint4*)(Ysrc + ks + 32);
            ga = *(const uint4*)(Gsrc + ks + 32);
        }
        short8 b  = *(const short8*)&Gs[(w*16 + lm)*40 + quad*8];
        short8 a0 = *(const short8*)&Ys[(lm)*40      + quad*8];
        short8 a1 = *(const short8*)&Ys[(16 + lm)*40 + quad*8];
        short8 a2 = *(const short8*)&Ys[(32 + lm)*40 + quad*8];
        short8 a3 = *(const short8*)&Ys[(48 + lm)*40 + quad*8];
        acc0 = __builtin_amdgcn_mfma_f32_16x16x32_bf16(a0, b, acc0, 0, 0, 0);
        acc1 = __builtin_amdgcn_mfma_f32_16x16x32_bf16(a1, b, acc1, 0, 0, 0);
        acc2 = __builtin_amdgcn_mfma_f32_16x16x32_bf16(a2, b, acc2, 0, 0, 0);
        acc3 = __builtin_amdgcn_mfma_f32_16x16x32_bf16(a3, b, acc3, 0, 0, 0);
        __syncthreads();
    }
    int col = w*16 + lm;
    #pragma unroll
    for (int rr = 0; rr < 4; rr++) {
        int row = m0 + quad*4 + rr;
        atomicAdd(&out[(size_t)row*FD + col],        acc0[rr] * mask[row]);
        atomicAdd(&out[(size_t)(row+16)*FD + col],   acc1[rr] * mask[row+16]);
        atomicAdd(&out[(size_t)(row+32)*FD + col],   acc2[rr] * mask[row+32]);
        atomicAdd(&out[(size_t)(row+48)*FD + col],   acc3[rr] * mask[row+48]);
    }
}

extern "C" void kernel_launch(void* const* d_in, const int* in_sizes, int n_in,
                              void* d_out, int out_size, void* d_ws, size_t ws_size,
                              hipStream_t stream) {
    const float* x    = (const float*)d_in[0];
    const float* adj  = (const float*)d_in[1];
    const float* mask = (const float*)d_in[2];
    const float* Wl   = (const float*)d_in[3];
    const float* bl   = (const float*)d_in[4];
    const float* Wr   = (const float*)d_in[5];
    const float* br   = (const float*)d_in[6];
    const float* Wm   = (const float*)d_in[9];
    const float* bm   = (const float*)d_in[10];
    float* out = (float*)d_out;
    float* ws  = (float*)d_ws;

    float* sumxp = ws + OFF_SUMXP;
    unsigned short* GmT = (unsigned short*)(ws + OFF_GMT);
    float* xl   = ws + OFF_XL;
    float* xr   = ws + OFF_XR;
    float* agg  = ws + OFF_AGG;
    unsigned short* Yb = (unsigned short*)(ws + OFF_Y);
    float* G1p  = ws + OFF_G1P;
    float* Wt   = ws + OFF_WT;

    hipLaunchKernelGGL(fused_pre_kernel, dim3(1352), dim3(256), 0, stream,
                       x, Wl, bl, Wr, br, Wm, bm, mask, xl, xr, sumxp, G1p, Wt, out);
    hipLaunchKernelGGL(fused_mid_kernel, dim3(2113), dim3(256), 0, stream,
                       x, adj, xl, xr, sumxp, G1p, agg, GmT);
    hipLaunchKernelGGL(ay_kernel, dim3(256, 8), dim3(256), 0, stream, agg, Wt, Yb);
    hipLaunchKernelGGL(gemm_kernel, dim3(32, KSPLIT), dim3(256), 0, stream, Yb, GmT, mask, out);
}